// Round 7
// baseline (47.893 us; speedup 1.0000x reference)
//
#include <hip/hip_runtime.h>

// Peg-solitaire batched env step — wave-autonomous, register-forwarded
// pegs-out edition. n = 262144. Each 64-lane wave owns 64 envs end-to-end.
//
// Key changes vs R5 (44.5 us):
//  * staging loads hand-unrolled: 9 independent f4 loads all in flight
//  * pegs_out written DIRECTLY from staging registers (write stream starts
//    during the load phase); 3 jump cells patched in global after vmcnt(0)
//  * scalar loads issued first (their stores fill the load bubble)
//  * states loop identical to R5 (isolate one structural change)
//
// Inputs: 0 pegs f32(n,33) | 1 n_pegs i32(n) | 2 done bool(n)
//         3 total_reward f32(n) | 4 actions i32(n)
//         5 pos_ids(132) | 6 mid_idx(132) | 7 tgt_idx(132) (OOB->0 encoded)
//         8 oob (unused) | 9 i_ind(33) | 10 j_ind(33)
// Output flat f32 (184n): rewards[0,n) | states[n,148n) | done[148n,149n)
//  | pegs[149n,182n) | n_pegs[182n,183n) | total_reward[183n,184n)

#define NTH 256
#define WPB 4      // waves per block
#define EPW 64     // envs per wave

typedef float f32x4 __attribute__((ext_vector_type(4)));

// cell k -> grid bit (i*7+j); used ONLY with compile-time (unrolled) indices.
__device__ constexpr int C2B[33] = {
    24,  2,  3,  4,  9, 10, 11, 14, 15, 16, 17, 18, 19, 20,
    21, 22, 23, 25, 26, 27, 28, 29, 30, 31, 32, 33, 34,
    37, 38, 39, 44, 45, 46};

constexpr unsigned long long cross_mask() {
    unsigned long long b = 0;
    for (int i = 0; i < 7; ++i)
        for (int j = 0; j < 7; ++j)
            if ((i >= 2 && i <= 4) || (j >= 2 && j <= 4))
                b |= 1ull << (i * 7 + j);
    return b;
}
constexpr unsigned long long cols_le(int jmax) {
    unsigned long long b = 0;
    for (int i = 0; i < 7; ++i)
        for (int j = 0; j <= jmax; ++j) b |= 1ull << (i * 7 + j);
    return b;
}
constexpr unsigned long long cols_ge(int jmin) {
    unsigned long long b = 0;
    for (int i = 0; i < 7; ++i)
        for (int j = jmin; j < 7; ++j) b |= 1ull << (i * 7 + j);
    return b;
}
constexpr unsigned long long B_MASK = cross_mask();
constexpr unsigned long long C_LE4  = cols_le(4);   // sources of j+1 jumps
constexpr unsigned long long C_GE2  = cols_ge(2);   // sources of j-1 jumps

// Intra-wave LDS fence: all prior ds ops by this wave complete & visible.
__device__ __forceinline__ void wave_lds_fence() {
    asm volatile("s_waitcnt lgkmcnt(0)" ::: "memory");
    __builtin_amdgcn_sched_barrier(0);   // rule #18 insurance
}

__global__ __launch_bounds__(NTH) void peg_step(
    const float* __restrict__ pegs_in,
    const int* __restrict__ n_pegs_in,
    const unsigned char* __restrict__ done_in,
    const float* __restrict__ tot_rew_in,
    const int* __restrict__ actions,
    const int* __restrict__ pos_ids,
    const int* __restrict__ mid_idx,
    const int* __restrict__ tgt_idx,
    const int* __restrict__ i_ind,
    const int* __restrict__ j_ind,
    float* __restrict__ out,
    int n)
{
    __shared__ __align__(16) float s_pegs[WPB][EPW * 33];   // 33.8 KB
    __shared__ unsigned long long s_bb[WPB][EPW];
    __shared__ float s_r1[WPB][EPW], s_r2[WPB][EPW];

    const int t    = threadIdx.x;
    const int w    = t >> 6;
    const int lane = t & 63;
    const int ew0  = blockIdx.x * (WPB * EPW) + w * EPW;   // wave's first env
    const int e    = ew0 + lane;

    // ---- Scalar loads FIRST (oldest in vmcnt queue -> earliest usable).
    const int a         = actions[e];
    const int np_new    = n_pegs_in[e] - 1;
    const bool done_old = (done_in[e] != 0);
    const float tot     = tot_rew_in[e];
    const int p = pos_ids[a], m = mid_idx[a], g = tgt_idx[a];   // OOB->0
    const int bp = i_ind[p] * 7 + j_ind[p];
    const int bm = i_ind[m] * 7 + j_ind[m];
    const int bg = i_ind[g] * 7 + j_ind[g];

    // ---- Staging: 9 INDEPENDENT f4 loads issued back-to-back, then
    //      forwarded to BOTH LDS (for the bitboard transpose) and pegs_out
    //      (the 35MB write stream starts at first load-return).
    float* pegs_out = out + (size_t)149 * n;
    {
        const f32x4* src  = (const f32x4*)(pegs_in + (size_t)ew0 * 33);
        f32x4* dstg       = (f32x4*)(pegs_out + (size_t)ew0 * 33);
        f32x4* dsts       = (f32x4*)s_pegs[w];
        f32x4 r[8], r8;
        #pragma unroll
        for (int k = 0; k < 8; ++k) r[k] = src[lane + 64 * k];   // 528 = 8*64+16
        if (lane < 16) r8 = src[512 + lane];
        #pragma unroll
        for (int k = 0; k < 8; ++k) {
            dsts[lane + 64 * k] = r[k];
            dstg[lane + 64 * k] = r[k];
        }
        if (lane < 16) {
            dsts[512 + lane] = r8;
            dstg[512 + lane] = r8;
        }
    }

    // ---- Early scalar outputs (fill the load bubble).
    const float rw  = (np_new == 1) ? 1.0f : (1.0f / 31.0f);
    const float npf = (float)np_new;
    out[e]                   = rw;          // rewards
    out[(size_t)182 * n + e] = npf;         // n_pegs
    out[(size_t)183 * n + e] = tot + rw;    // total_reward

    wave_lds_fence();   // staged rows visible wave-wide

    // ---- Own-row bitboard (compile-time shifts) + bit-level jump patch.
    const float* row = s_pegs[w] + lane * 33;
    unsigned long long P = 0;
    #pragma unroll
    for (int c = 0; c < 33; ++c)
        P |= (unsigned long long)(row[c] != 0.0f) << C2B[c];

    // order pos<-0, mid<-0, tgt<-1 (aliasing when OOB defaults to cell 0)
    P &= ~(1ull << bp);
    P &= ~(1ull << bm);
    P |=  (1ull << bg);

    // ---- Patch the 3 jump cells in global pegs_out. vmcnt(0) orders the
    //      patches after this wave's own f4 stream (same lines, L2-dirty).
    asm volatile("s_waitcnt vmcnt(0)" ::: "memory");
    {
        float* od = pegs_out + (size_t)e * 33;
        od[p] = 0.0f;
        od[m] = 0.0f;
        od[g] = 1.0f;
    }

    // ---- Feasibility over all 132 actions in ~15 wide ops
    const unsigned long long E = ~P & B_MASK;
    const unsigned long long feas =
        (P & (P >> 1) & (E >> 2)  & C_LE4) |   // j+1
        (P & (P << 1) & (E << 2)  & C_GE2) |   // j-1
        (P & (P >> 7) & (E >> 14))         |   // i+1
        (P & (P << 7) & (E << 14));            // i-1

    const bool dn = (np_new == 1) | done_old | (feas == 0ull);
    out[(size_t)148 * n + e] = dn ? 1.0f : 0.0f;    // done

    s_bb[w][lane] = P;
    s_r1[w][lane] = (npf - 1.0f)  * (1.0f / 31.0f);   // peg_ratio
    s_r2[w][lane] = (32.0f - npf) * (1.0f / 31.0f);   // removed_ratio

    wave_lds_fence();   // bb/ratios visible wave-wide

    // ---- States (env,7,7,3) for this wave's 64 envs, coalesced f4.
    //      Identical to R5. el = rc*3+ch; ch0 = grid bit rc; ch1/ch2 ratios.
    {
        f32x4* dst = (f32x4*)(out + (size_t)n + (size_t)ew0 * 147);
        const int total = EPW * 147 / 4;              // 2352
        for (int q = lane; q < total; q += 64) {
            const int f4 = q * 4;
            int env = f4 / 147;                       // magic-mul
            int el  = f4 - env * 147;
            unsigned long long bb = s_bb[w][env];
            float r1 = s_r1[w][env], r2 = s_r2[w][env];
            f32x4 v;
            #pragma unroll
            for (int r = 0; r < 4; ++r) {
                if (el == 147) {                      // env boundary
                    el = 0; ++env;
                    bb = s_bb[w][env]; r1 = s_r1[w][env]; r2 = s_r2[w][env];
                }
                const int rc = el / 3;                // magic-mul
                const int ch = el - rc * 3;
                v[r] = (ch == 0) ? (float)((unsigned int)(bb >> rc) & 1u)
                                 : ((ch == 1) ? r1 : r2);
                ++el;
            }
            dst[q] = v;
        }
    }
}

extern "C" void kernel_launch(void* const* d_in, const int* in_sizes, int n_in,
                              void* d_out, int out_size, void* d_ws, size_t ws_size,
                              hipStream_t stream) {
    const float* pegs          = (const float*)d_in[0];
    const int* n_pegs          = (const int*)d_in[1];
    const unsigned char* done  = (const unsigned char*)d_in[2];
    const float* total_reward  = (const float*)d_in[3];
    const int* actions         = (const int*)d_in[4];
    const int* pos_ids         = (const int*)d_in[5];
    const int* mid_idx         = (const int*)d_in[6];
    const int* tgt_idx         = (const int*)d_in[7];
    // d_in[8] oob_mask unused (tables already encode OOB->0)
    const int* i_ind           = (const int*)d_in[9];
    const int* j_ind           = (const int*)d_in[10];
    float* out = (float*)d_out;

    int n = in_sizes[1];                    // 262144, divisible by 256
    dim3 grid(n / (WPB * EPW)), block(NTH);
    hipLaunchKernelGGL(peg_step, grid, block, 0, stream,
                       pegs, n_pegs, done, total_reward, actions,
                       pos_ids, mid_idx, tgt_idx, i_ind, j_ind, out, n);
}

// Round 8
// 44.832 us; speedup vs baseline: 1.0683x; 1.0683x over previous
//
#include <hip/hip_runtime.h>

// Peg-solitaire batched env step — cell-space atomic bitboard edition.
// n = 262144. Each 64-lane wave owns 64 envs end-to-end; no __syncthreads.
//
// Key change vs R5 (44.5 us): NO 33KB LDS row staging / transpose. Each lane
// converts its 9 coalesced f4 load chunks into 4-bit peg masks and ds_or_b64s
// them into a per-env 33-bit CELL mask (bit k = cell k). Jump patch happens in
// cell space (no i/j table gathers); one unrolled const-shift pass converts to
// the 7x7 GRID mask for feasibility; pegs_out is re-generated from the patched
// cell mask (values are exactly {0,1}). LDS 37KB -> 7KB => 24-32 waves/CU.
//
// Inputs: 0 pegs f32(n,33) | 1 n_pegs i32(n) | 2 done bool(n)
//         3 total_reward f32(n) | 4 actions i32(n)
//         5 pos_ids(132) | 6 mid_idx(132) | 7 tgt_idx(132) (OOB->0 encoded)
//         8 oob (unused) | 9 i_ind (unused) | 10 j_ind (unused)
// Output flat f32 (184n): rewards[0,n) | states[n,148n) | done[148n,149n)
//  | pegs[149n,182n) | n_pegs[182n,183n) | total_reward[183n,184n)

#define NTH 256
#define WPB 4      // waves per block
#define EPW 64     // envs per wave

typedef float f32x4 __attribute__((ext_vector_type(4)));

// cell k -> grid bit (i*7+j); used ONLY with compile-time (unrolled) indices.
__device__ constexpr int C2B[33] = {
    24,  2,  3,  4,  9, 10, 11, 14, 15, 16, 17, 18, 19, 20,
    21, 22, 23, 25, 26, 27, 28, 29, 30, 31, 32, 33, 34,
    37, 38, 39, 44, 45, 46};

constexpr unsigned long long MASK33 = (1ull << 33) - 1;

constexpr unsigned long long cross_mask() {
    unsigned long long b = 0;
    for (int i = 0; i < 7; ++i)
        for (int j = 0; j < 7; ++j)
            if ((i >= 2 && i <= 4) || (j >= 2 && j <= 4))
                b |= 1ull << (i * 7 + j);
    return b;
}
constexpr unsigned long long cols_le(int jmax) {
    unsigned long long b = 0;
    for (int i = 0; i < 7; ++i)
        for (int j = 0; j <= jmax; ++j) b |= 1ull << (i * 7 + j);
    return b;
}
constexpr unsigned long long cols_ge(int jmin) {
    unsigned long long b = 0;
    for (int i = 0; i < 7; ++i)
        for (int j = jmin; j < 7; ++j) b |= 1ull << (i * 7 + j);
    return b;
}
constexpr unsigned long long B_MASK = cross_mask();
constexpr unsigned long long C_LE4  = cols_le(4);   // sources of j+1 jumps
constexpr unsigned long long C_GE2  = cols_ge(2);   // sources of j-1 jumps

// Intra-wave LDS fence: all prior ds ops by this wave complete & visible.
__device__ __forceinline__ void wave_lds_fence() {
    asm volatile("s_waitcnt lgkmcnt(0)" ::: "memory");
    __builtin_amdgcn_sched_barrier(0);   // rule #18 insurance
}

__global__ __launch_bounds__(NTH, 6) void peg_step(
    const float* __restrict__ pegs_in,
    const int* __restrict__ n_pegs_in,
    const unsigned char* __restrict__ done_in,
    const float* __restrict__ tot_rew_in,
    const int* __restrict__ actions,
    const int* __restrict__ pos_ids,
    const int* __restrict__ mid_idx,
    const int* __restrict__ tgt_idx,
    float* __restrict__ out,
    int n)
{
    // s_cm padded to EPW+1: pegs-out concat-read touches [env+1] (value
    // never used when env==63 since those chunks don't cross; pad only
    // avoids an OOB LDS address).
    __shared__ unsigned long long s_cm[WPB][EPW + 1];   // cell masks
    __shared__ unsigned long long s_bb[WPB][EPW];       // grid masks
    __shared__ float s_r1[WPB][EPW], s_r2[WPB][EPW];

    const int t    = threadIdx.x;
    const int w    = t >> 6;
    const int lane = t & 63;
    const int ew0  = blockIdx.x * (WPB * EPW) + w * EPW;   // wave's first env
    const int e    = ew0 + lane;

    // Zero own accumulator (DS ops are in-order per wave -> no fence needed
    // before the atomics below, which come later in program order).
    s_cm[w][lane] = 0ull;

    // ---- Staging: 9 coalesced f4 loads, all independent, issued early.
    const f32x4* src = (const f32x4*)(pegs_in + (size_t)ew0 * 33);
    f32x4 r[8], r8;
    #pragma unroll
    for (int k = 0; k < 8; ++k) r[k] = src[lane + 64 * k];   // 528 = 8*64+16
    if (lane < 16) r8 = src[512 + lane];

    // ---- Scalar loads + early scalar outputs (fill the load bubble).
    const int a         = actions[e];
    const int np_new    = n_pegs_in[e] - 1;
    const bool done_old = (done_in[e] != 0);
    const float tot     = tot_rew_in[e];
    const int p = pos_ids[a], m = mid_idx[a], g = tgt_idx[a];   // OOB->0

    const float rw  = (np_new == 1) ? 1.0f : (1.0f / 31.0f);
    const float npf = (float)np_new;
    out[e]                   = rw;          // rewards
    out[(size_t)182 * n + e] = npf;         // n_pegs
    out[(size_t)183 * n + e] = tot + rw;    // total_reward

    // ---- Accumulate cell-mask bits: one ds_or_b64 per chunk (+1 on the
    //      3-in-4 chunks that straddle an env boundary).
    {
        unsigned long long* cm = s_cm[w];
        #pragma unroll
        for (int k = 0; k < 8; ++k) {
            const int q   = lane + 64 * k;
            const int f   = q * 4;
            const int env = f / 33;                  // magic-mul (const div)
            const int c   = f - env * 33;
            const unsigned mm = (r[k][0] != 0.0f) | ((r[k][1] != 0.0f) << 1) |
                                ((r[k][2] != 0.0f) << 2) | ((r[k][3] != 0.0f) << 3);
            const unsigned long long full = (unsigned long long)mm << c;
            atomicOr(&cm[env], full & MASK33);
            const unsigned long long hi = full >> 33;
            if (hi) atomicOr(&cm[env + 1], hi);
        }
        if (lane < 16) {
            const int q   = 512 + lane;
            const int f   = q * 4;
            const int env = f / 33;
            const int c   = f - env * 33;
            const unsigned mm = (r8[0] != 0.0f) | ((r8[1] != 0.0f) << 1) |
                                ((r8[2] != 0.0f) << 2) | ((r8[3] != 0.0f) << 3);
            const unsigned long long full = (unsigned long long)mm << c;
            atomicOr(&cm[env], full & MASK33);
            const unsigned long long hi = full >> 33;
            if (hi) atomicOr(&cm[env + 1], hi);
        }
    }

    wave_lds_fence();   // all lanes' ORs into this wave's segment complete

    // ---- Own-env cell mask: patch jump in CELL space.
    //      order pos<-0, mid<-0, tgt<-1 (aliasing when OOB defaults to 0)
    unsigned long long cm = s_cm[w][lane];
    cm &= ~(1ull << p);
    cm &= ~(1ull << m);
    cm |=  (1ull << g);

    // ---- Cell -> grid conversion (compile-time shifts), feasibility.
    unsigned long long P = 0;
    #pragma unroll
    for (int c = 0; c < 33; ++c)
        P |= ((cm >> c) & 1ull) << C2B[c];

    const unsigned long long E = ~P & B_MASK;
    const unsigned long long feas =
        (P & (P >> 1) & (E >> 2)  & C_LE4) |   // j+1
        (P & (P << 1) & (E << 2)  & C_GE2) |   // j-1
        (P & (P >> 7) & (E >> 14))         |   // i+1
        (P & (P << 7) & (E << 14));            // i-1

    const bool dn = (np_new == 1) | done_old | (feas == 0ull);
    out[(size_t)148 * n + e] = dn ? 1.0f : 0.0f;    // done

    s_cm[w][lane] = cm;                              // patched, for pegs-out
    s_bb[w][lane] = P;                               // grid, for states ch0
    s_r1[w][lane] = (npf - 1.0f)  * (1.0f / 31.0f);  // peg_ratio
    s_r2[w][lane] = (32.0f - npf) * (1.0f / 31.0f);  // removed_ratio

    wave_lds_fence();   // patched masks + ratios visible wave-wide

    // ---- pegs out: regenerate from patched cell masks (values are {0,1}).
    //      Branchless env-boundary handling via 2-entry concat.
    {
        f32x4* dst = (f32x4*)(out + (size_t)149 * n + (size_t)ew0 * 33);
        #pragma unroll
        for (int k = 0; k < 9; ++k) {
            const int q = lane + 64 * k;
            if (k < 8 || lane < 16) {                // q < 528
                const int f   = q * 4;
                const int env = f / 33;              // magic-mul
                const int c   = f - env * 33;
                const unsigned long long cat =
                    s_cm[w][env] | (s_cm[w][env + 1] << 33);
                f32x4 v;
                #pragma unroll
                for (int rr = 0; rr < 4; ++rr)
                    v[rr] = (float)((unsigned int)(cat >> (c + rr)) & 1u);
                dst[q] = v;
            }
        }
    }

    // ---- States (env,7,7,3): identical to R5. el = rc*3+ch; ch0 = grid bit
    //      rc of bb; ch1/ch2 = ratios.
    {
        f32x4* dst = (f32x4*)(out + (size_t)n + (size_t)ew0 * 147);
        const int total = EPW * 147 / 4;              // 2352
        for (int q = lane; q < total; q += 64) {
            const int f4 = q * 4;
            int env = f4 / 147;                       // magic-mul
            int el  = f4 - env * 147;
            unsigned long long bb = s_bb[w][env];
            float r1 = s_r1[w][env], r2 = s_r2[w][env];
            f32x4 v;
            #pragma unroll
            for (int rr = 0; rr < 4; ++rr) {
                if (el == 147) {                      // env boundary
                    el = 0; ++env;
                    bb = s_bb[w][env]; r1 = s_r1[w][env]; r2 = s_r2[w][env];
                }
                const int rc = el / 3;                // magic-mul
                const int ch = el - rc * 3;
                v[rr] = (ch == 0) ? (float)((unsigned int)(bb >> rc) & 1u)
                                  : ((ch == 1) ? r1 : r2);
                ++el;
            }
            dst[q] = v;
        }
    }
}

extern "C" void kernel_launch(void* const* d_in, const int* in_sizes, int n_in,
                              void* d_out, int out_size, void* d_ws, size_t ws_size,
                              hipStream_t stream) {
    const float* pegs          = (const float*)d_in[0];
    const int* n_pegs          = (const int*)d_in[1];
    const unsigned char* done  = (const unsigned char*)d_in[2];
    const float* total_reward  = (const float*)d_in[3];
    const int* actions         = (const int*)d_in[4];
    const int* pos_ids         = (const int*)d_in[5];
    const int* mid_idx         = (const int*)d_in[6];
    const int* tgt_idx         = (const int*)d_in[7];
    // d_in[8] oob_mask, d_in[9] i_ind, d_in[10] j_ind: unused (cell-space
    // patch + constexpr grid mapping).
    float* out = (float*)d_out;

    int n = in_sizes[1];                    // 262144, divisible by 256
    dim3 grid(n / (WPB * EPW)), block(NTH);
    hipLaunchKernelGGL(peg_step, grid, block, 0, stream,
                       pegs, n_pegs, done, total_reward, actions,
                       pos_ids, mid_idx, tgt_idx, out, n);
}